// Round 7
// baseline (204.615 us; speedup 1.0000x reference)
//
#include <hip/hip_runtime.h>
#include <hip/hip_bf16.h>

typedef float f32x4  __attribute__((ext_vector_type(4)));
typedef float f32x16 __attribute__((ext_vector_type(16)));
typedef short s16x8  __attribute__((ext_vector_type(8)));
typedef unsigned short u16;

#define B_ 4
#define C_ 512
#define H_ 128
#define W_ 128
#define NO_ 640   // 64 q + 64 k + 512 v output channels

__device__ __forceinline__ u16 f2bf(float f) {
    __hip_bfloat16 h = __float2bfloat16(f);
    union { __hip_bfloat16 h; u16 u; } cv; cv.h = h; return cv.u;
}
__device__ __forceinline__ float bf2f(u16 u) {
    union { unsigned u; float f; } cv; cv.u = ((unsigned)u) << 16; return cv.f;
}

// async global->LDS, 16B per lane; LDS dest must be wave_base + lane*16
__device__ __forceinline__ void gld16(const u16* g, u16* l) {
    __builtin_amdgcn_global_load_lds(
        (const __attribute__((address_space(1))) void*)g,
        (__attribute__((address_space(3))) void*)l, 16, 0, 0);
}

// ---------------------------------------------------------------- K0: weights
__global__ __launch_bounds__(256) void k_convw(const float* __restrict__ Wq, const float* __restrict__ bq,
                                               const float* __restrict__ Wk, const float* __restrict__ bk,
                                               const float* __restrict__ Wv, const float* __restrict__ bv,
                                               u16* __restrict__ Wcat, float* __restrict__ bcat) {
    const int idx = blockIdx.x * 256 + threadIdx.x;
    if (idx < NO_ * C_) {
        const int o = idx >> 9, c = idx & 511;
        float v;
        if (o < 64)       v = Wq[o * C_ + c];
        else if (o < 128) v = Wk[(o - 64) * C_ + c];
        else              v = Wv[(o - 128) * C_ + c];
        Wcat[idx] = f2bf(v);
    }
    if (idx < NO_) {
        float v = (idx < 64) ? bq[idx] : ((idx < 128) ? bk[idx - 64] : bv[idx - 128]);
        bcat[idx] = v;
    }
}

// ------------------------------------------------- K1: x[B,C,H,W] -> xT[b][w][h][c] bf16
__global__ __launch_bounds__(256) void k_transpose_x(const float* __restrict__ x, u16* __restrict__ xT) {
    __shared__ float tile[64][65];
    const int b  = blockIdx.x >> 7;
    const int h  = blockIdx.x & 127;
    const int c0 = (blockIdx.y >> 1) * 64;
    const int w0 = (blockIdx.y & 1) * 64;
    const int t = threadIdx.x, r = t >> 4, seg = t & 15;
    const float* xp = x + (size_t)b * C_ * H_ * W_ + (size_t)h * W_;
#pragma unroll
    for (int rr = 0; rr < 4; ++rr) {
        const int c = rr * 16 + r;
        float4 v = *(const float4*)(xp + (size_t)(c0 + c) * (H_ * W_) + w0 + seg * 4);
        tile[c][seg * 4 + 0] = v.x; tile[c][seg * 4 + 1] = v.y;
        tile[c][seg * 4 + 2] = v.z; tile[c][seg * 4 + 3] = v.w;
    }
    __syncthreads();
#pragma unroll
    for (int rr = 0; rr < 4; ++rr) {
        const int w = rr * 16 + r;
        ushort4 u;
        u.x = f2bf(tile[seg * 4 + 0][w]); u.y = f2bf(tile[seg * 4 + 1][w]);
        u.z = f2bf(tile[seg * 4 + 2][w]); u.w = f2bf(tile[seg * 4 + 3][w]);
        *(ushort4*)(xT + ((size_t)((b * W_ + w0 + w) * H_ + h)) * C_ + c0 + seg * 4) = u;
    }
}

// ------------------------------------------------- K2: GEMM, m201 geometry
// BM=256, BN=256, BK=64, 8 waves (2M x 4N), wave tile 128x64, 32x32x16 MFMA.
// dbuf-2 LDS (2 x 64KB), depth-1 prefetch, counted vmcnt(8).
// T2 seg-XOR swizzle (seg_phys = seg_log ^ (row&7)); gld16 dest linear,
// global source pre-swizzled. N=640 -> 3 n-tiles (256,256,128+pad).
__global__ __launch_bounds__(512, 2) void k_gemm(const u16* __restrict__ A, const u16* __restrict__ Wc,
                                                 const float* __restrict__ bias, u16* __restrict__ Call,
                                                 u16* __restrict__ vt) {
    __shared__ __align__(16) u16 smem[65536];   // 128 KB: 2 slots of (A 16384 + B 16384) u16
    const int t = threadIdx.x;
    const int lane = t & 63;
    const int wave = t >> 6;
    const int wr = wave >> 2;          // M half (128 rows)
    const int wc = wave & 3;           // N quarter (64 cols)
    const int l31 = lane & 31;
    const int kh = lane >> 5;          // k-half within fragment

    // bijective XCD-chunk swizzle: 768 = 8 XCDs x 96; n fastest within a panel
    const int bid = blockIdx.x;
    const int wg = (bid & 7) * 96 + (bid >> 3);
    const int panel = wg / 3;
    const int n = wg - panel * 3;
    const int r0 = panel * 256;
    const int n0 = n * 256;

    // staging: thread t covers (row = t>>3 within each 64-row round, seg_phys = t&7)
    const int srow = t >> 3;
    const int slog = (t & 7) ^ (srow & 7);         // inverse-swizzled source segment
    const u16* gA = A + (size_t)(r0 + srow) * C_ + slog * 8;
    const u16* gBr[4];
#pragma unroll
    for (int i = 0; i < 4; ++i) {
        int row = n0 + i * 64 + srow;
        if (row > NO_ - 1) row = NO_ - 1;          // tail clamp (valid-but-unused)
        gBr[i] = Wc + (size_t)row * C_ + slog * 8;
    }

#define STAGE(KT) do {                                                 \
        u16* S_ = smem + ((KT) & 1) * 32768;                           \
        const int k0_ = (KT) * 64;                                     \
        gld16(gA + k0_,             S_ + t * 8);                       \
        gld16(gA + k0_ +  64 * C_,  S_ + 4096  + t * 8);               \
        gld16(gA + k0_ + 128 * C_,  S_ + 8192  + t * 8);               \
        gld16(gA + k0_ + 192 * C_,  S_ + 12288 + t * 8);               \
        gld16(gBr[0] + k0_,         S_ + 16384 + t * 8);               \
        gld16(gBr[1] + k0_,         S_ + 20480 + t * 8);               \
        gld16(gBr[2] + k0_,         S_ + 24576 + t * 8);               \
        gld16(gBr[3] + k0_,         S_ + 28672 + t * 8);               \
    } while (0)

    f32x16 acc[4][2] = {};
    STAGE(0);

#pragma unroll
    for (int T = 0; T < 8; ++T) {
        if (T < 7) {
            STAGE(T + 1);
            asm volatile("s_waitcnt vmcnt(8)" ::: "memory");   // tile T landed; T+1 in flight
        } else {
            asm volatile("s_waitcnt vmcnt(0)" ::: "memory");
        }
        __builtin_amdgcn_s_barrier();
        const u16* Ab = smem + (T & 1) * 32768;
        const u16* Bb = Ab + 16384;
#pragma unroll
        for (int kl = 0; kl < 4; ++kl) {
            const int sb = kl * 2 + kh;                        // logical 16B segment
            s16x8 fa[4], fb[2];
#pragma unroll
            for (int mi = 0; mi < 4; ++mi) {
                const int rr = wr * 128 + mi * 32 + l31;
                fa[mi] = *(const s16x8*)&Ab[rr * 64 + ((sb ^ (rr & 7)) * 8)];
            }
#pragma unroll
            for (int ni = 0; ni < 2; ++ni) {
                const int rr = wc * 64 + ni * 32 + l31;
                fb[ni] = *(const s16x8*)&Bb[rr * 64 + ((sb ^ (rr & 7)) * 8)];
            }
            __builtin_amdgcn_s_setprio(1);
#pragma unroll
            for (int mi = 0; mi < 4; ++mi)
#pragma unroll
                for (int ni = 0; ni < 2; ++ni)
                    acc[mi][ni] = __builtin_amdgcn_mfma_f32_32x32x16_bf16(
                        fa[mi], fb[ni], acc[mi][ni], 0, 0, 0);
            __builtin_amdgcn_s_setprio(0);
        }
        __builtin_amdgcn_s_barrier();
    }
#undef STAGE

    // C/D mapping (m74/m101): col = lane&31, row = (reg&3) + 8*(reg>>2) + 4*(lane>>5)
    const int bw0 = panel * 2;
    if (n == 0 && wc < 2) {
        // Q/K: cols o = wc*64 + ni*32 + l31 (0..127) -> Call[row][o]
#pragma unroll
        for (int ni = 0; ni < 2; ++ni) {
            const int o = wc * 64 + ni * 32 + l31;
            const float bz = bias[o];
#pragma unroll
            for (int mi = 0; mi < 4; ++mi)
#pragma unroll
                for (int rg = 0; rg < 16; ++rg) {
                    const int row = r0 + wr * 128 + mi * 32 + (rg & 3) + 8 * (rg >> 2) + 4 * kh;
                    Call[(size_t)row * 128 + o] = f2bf(acc[mi][ni][rg] + bz);
                }
        }
    }
    // V: transpose passes of 128 channels through T[128][264]
    u16* Tt = smem;
#pragma unroll
    for (int pass = 0; pass < 2; ++pass) {
        const int base = n0 + pass * 128;          // global col of pass start
        if (base < 128 || base >= NO_) continue;   // n=0 pass0 = Q/K; n=2 pass1 = OOB pad
        if ((wc >> 1) == pass) {
#pragma unroll
            for (int ni = 0; ni < 2; ++ni) {
                const int c_loc = (wc & 1) * 64 + ni * 32 + l31;    // 0..127
                const float bz = bias[base + c_loc];
#pragma unroll
                for (int mi = 0; mi < 4; ++mi)
#pragma unroll
                    for (int q = 0; q < 4; ++q) {
                        const int hb = wr * 128 + mi * 32 + q * 8 + 4 * kh;  // 4 consecutive rows
                        ushort4 u4;
                        u4.x = f2bf(acc[mi][ni][q * 4 + 0] + bz);
                        u4.y = f2bf(acc[mi][ni][q * 4 + 1] + bz);
                        u4.z = f2bf(acc[mi][ni][q * 4 + 2] + bz);
                        u4.w = f2bf(acc[mi][ni][q * 4 + 3] + bz);
                        *(ushort4*)&Tt[c_loc * 264 + hb] = u4;
                    }
            }
        }
        __syncthreads();
        {
            const int c_loc = t >> 2, h0 = (t & 3) * 64;
            const int cg = base - 128 + c_loc;                      // V channel 0..511
#pragma unroll
            for (int k = 0; k < 8; ++k) {
                const int h = h0 + k * 8;                           // 0..255
                const int bw = bw0 + (h >> 7);
                s16x8 v = *(const s16x8*)&Tt[c_loc * 264 + h];
                *(s16x8*)&vt[((size_t)bw * 512 + cg) * 128 + (h & 127)] = v;
            }
        }
        __syncthreads();
    }
}

// ------------------------------------------------- K4: per-(b,w) axial attention
__global__ __launch_bounds__(256) void k_attn(const u16* __restrict__ Call, const u16* __restrict__ vt,
                                              u16* __restrict__ outws) {
    __shared__ __align__(16) float E[128][132];
    __shared__ float Rinv[128];
    const int bw = blockIdx.x;
    const int t = threadIdx.x;
    const int lane = t & 63;
    const int wr = t >> 7;
    const int wc = (t >> 6) & 1;
    const int lr = lane & 15, lk = (lane >> 4) * 8;
    const size_t rowbase = (size_t)bw * 128;

    // ---- energy = Q K^T  (K-dim = 64 channels); Call stride 128
    f32x4 e[4][4] = {};
#pragma unroll
    for (int kk = 0; kk < 2; ++kk) {
        s16x8 fq[4], fk[4];
#pragma unroll
        for (int mi = 0; mi < 4; ++mi)
            fq[mi] = *(const s16x8*)&Call[(rowbase + wr * 64 + mi * 16 + lr) * 128 + kk * 32 + lk];
#pragma unroll
        for (int ni = 0; ni < 4; ++ni)
            fk[ni] = *(const s16x8*)&Call[(rowbase + wc * 64 + ni * 16 + lr) * 128 + 64 + kk * 32 + lk];
#pragma unroll
        for (int mi = 0; mi < 4; ++mi)
#pragma unroll
            for (int ni = 0; ni < 4; ++ni)
                e[mi][ni] = __builtin_amdgcn_mfma_f32_16x16x32_bf16(fq[mi], fk[ni], e[mi][ni], 0, 0, 0);
    }
#pragma unroll
    for (int mi = 0; mi < 4; ++mi)
#pragma unroll
        for (int ni = 0; ni < 4; ++ni)
#pragma unroll
            for (int j = 0; j < 4; ++j)
                E[wr * 64 + mi * 16 + (lane >> 4) * 4 + j][wc * 64 + ni * 16 + lr] = e[mi][ni][j];
    __syncthreads();

    // ---- softmax over g (rows h), exp in place, 2 threads per row
    {
        const int h = t >> 1, hf = (t & 1) * 64;
        float m = -1e30f;
        for (int i = 0; i < 64; ++i) m = fmaxf(m, E[h][hf + i]);
        m = fmaxf(m, __shfl_xor(m, 1));
        float s = 0.f;
        for (int i = 0; i < 64; ++i) {
            float p = __expf(E[h][hf + i] - m);
            E[h][hf + i] = p;
            s += p;
        }
        s += __shfl_xor(s, 1);
        if ((t & 1) == 0) Rinv[h] = 1.0f / s;
    }
    __syncthreads();

    float rv[4][4];
#pragma unroll
    for (int mi = 0; mi < 4; ++mi)
#pragma unroll
        for (int j = 0; j < 4; ++j)
            rv[mi][j] = Rinv[wr * 64 + mi * 16 + (lane >> 4) * 4 + j];

    // ---- P rows -> bf16 fragments ONCE
    s16x8 pa[4][4];
#pragma unroll
    for (int kk = 0; kk < 4; ++kk)
#pragma unroll
        for (int mi = 0; mi < 4; ++mi) {
            const float* ep = &E[wr * 64 + mi * 16 + lr][kk * 32 + lk];
            float4 v0 = *(const float4*)ep;
            float4 v1 = *(const float4*)(ep + 4);
            s16x8 a;
            a[0] = (short)f2bf(v0.x); a[1] = (short)f2bf(v0.y);
            a[2] = (short)f2bf(v0.z); a[3] = (short)f2bf(v0.w);
            a[4] = (short)f2bf(v1.x); a[5] = (short)f2bf(v1.y);
            a[6] = (short)f2bf(v1.z); a[7] = (short)f2bf(v1.w);
            pa[kk][mi] = a;
        }

    // ---- out = P V
    for (int cc = 0; cc < 4; ++cc) {
        f32x4 acc[4][4] = {};
#pragma unroll
        for (int kk = 0; kk < 4; ++kk) {
            s16x8 fb[4];
#pragma unroll
            for (int ni = 0; ni < 4; ++ni)
                fb[ni] = *(const s16x8*)&vt[((size_t)bw * 512 + cc * 128 + wc * 64 + ni * 16 + lr) * 128 + kk * 32 + lk];
#pragma unroll
            for (int mi = 0; mi < 4; ++mi)
#pragma unroll
                for (int ni = 0; ni < 4; ++ni)
                    acc[mi][ni] = __builtin_amdgcn_mfma_f32_16x16x32_bf16(pa[kk][mi], fb[ni], acc[mi][ni], 0, 0, 0);
        }
#pragma unroll
        for (int ni = 0; ni < 4; ++ni) {
            const int c = cc * 128 + wc * 64 + ni * 16 + lr;
#pragma unroll
            for (int mi = 0; mi < 4; ++mi)
#pragma unroll
                for (int j = 0; j < 4; ++j) {
                    const int hh = wr * 64 + mi * 16 + (lane >> 4) * 4 + j;
                    outws[(rowbase + hh) * 512 + c] = f2bf(acc[mi][ni][j] * rv[mi][j]);
                }
        }
    }
}

// ------------------------------------------------- K5: out = gamma*out_ws^T + x
__global__ __launch_bounds__(256) void k_merge(const u16* __restrict__ outws, const float* __restrict__ x,
                                               const float* __restrict__ gamma, float* __restrict__ out) {
    __shared__ float tile[64][65];
    const int b  = blockIdx.x >> 7;
    const int h  = blockIdx.x & 127;
    const int c0 = (blockIdx.y >> 1) * 64;
    const int w0 = (blockIdx.y & 1) * 64;
    const float g = gamma[0];
    const int t = threadIdx.x, r = t >> 4, seg = t & 15;
#pragma unroll
    for (int rr = 0; rr < 4; ++rr) {
        const int w = rr * 16 + r;
        ushort4 v = *(const ushort4*)(outws + ((size_t)((b * W_ + w0 + w) * H_) + h) * C_ + c0 + seg * 4);
        tile[w][seg * 4 + 0] = bf2f(v.x); tile[w][seg * 4 + 1] = bf2f(v.y);
        tile[w][seg * 4 + 2] = bf2f(v.z); tile[w][seg * 4 + 3] = bf2f(v.w);
    }
    __syncthreads();
#pragma unroll
    for (int rr = 0; rr < 4; ++rr) {
        const int c = rr * 16 + r;
        const size_t base = ((size_t)(b * C_ + c0 + c) * H_ + h) * W_ + w0 + seg * 4;
        float4 xv = *(const float4*)(x + base);
        float4 o;
        o.x = g * tile[seg * 4 + 0][c] + xv.x;
        o.y = g * tile[seg * 4 + 1][c] + xv.y;
        o.z = g * tile[seg * 4 + 2][c] + xv.z;
        o.w = g * tile[seg * 4 + 3][c] + xv.w;
        *(float4*)(out + base) = o;
    }
}

extern "C" void kernel_launch(void* const* d_in, const int* in_sizes, int n_in,
                              void* d_out, int out_size, void* d_ws, size_t ws_size,
                              hipStream_t stream) {
    const float* x     = (const float*)d_in[0];
    const float* Wq    = (const float*)d_in[1];
    const float* bq    = (const float*)d_in[2];
    const float* Wk    = (const float*)d_in[3];
    const float* bk    = (const float*)d_in[4];
    const float* Wv    = (const float*)d_in[5];
    const float* bv    = (const float*)d_in[6];
    const float* gamma = (const float*)d_in[7];

    char* ws = (char*)d_ws;
    u16*   Wcat  = (u16*)ws;                                   //   0.66 MB
    float* bcat  = (float*)(ws + 655360);                      //   2.5 KB
    u16*   xT    = (u16*)(ws + (1u << 20));                    //  67.1 MB  (reused as out_ws)
    u16*   Call  = (u16*)(ws + (1u << 20) + 67108864);         //  16.8 MB  (Q/K only, stride 128)
    u16*   outws = xT;                                         //  xT dead after k_gemm
    u16*   vt    = (u16*)d_out;                                //  first 67 MB of d_out; dead before k_merge writes

    k_convw<<<dim3((NO_ * C_ + 255) / 256), 256, 0, stream>>>(Wq, bq, Wk, bk, Wv, bv, Wcat, bcat);
    k_transpose_x<<<dim3(B_ * H_, 16), 256, 0, stream>>>(x, xT);
    k_gemm<<<dim3(768), 512, 0, stream>>>(xT, Wcat, bcat, Call, vt);
    k_attn<<<dim3(B_ * W_), 256, 0, stream>>>(Call, vt, outws);
    k_merge<<<dim3(B_ * H_, 16), 256, 0, stream>>>(outws, x, gamma, (float*)d_out);
}

// Round 8
// 204.158 us; speedup vs baseline: 1.0022x; 1.0022x over previous
//
#include <hip/hip_runtime.h>
#include <hip/hip_bf16.h>

typedef float f32x4  __attribute__((ext_vector_type(4)));
typedef float f32x16 __attribute__((ext_vector_type(16)));
typedef short s16x8  __attribute__((ext_vector_type(8)));
typedef unsigned short u16;

#define B_ 4
#define C_ 512
#define H_ 128
#define W_ 128
#define NO_ 640   // 64 q + 64 k + 512 v output channels

__device__ __forceinline__ u16 f2bf(float f) {
    __hip_bfloat16 h = __float2bfloat16(f);
    union { __hip_bfloat16 h; u16 u; } cv; cv.h = h; return cv.u;
}
__device__ __forceinline__ float bf2f(u16 u) {
    union { unsigned u; float f; } cv; cv.u = ((unsigned)u) << 16; return cv.f;
}

// async global->LDS, 16B per lane; LDS dest must be wave_base + lane*16
__device__ __forceinline__ void gld16(const u16* g, u16* l) {
    __builtin_amdgcn_global_load_lds(
        (const __attribute__((address_space(1))) void*)g,
        (__attribute__((address_space(3))) void*)l, 16, 0, 0);
}

// ---------------------------------------------------------------- K0: weights
__global__ __launch_bounds__(256) void k_convw(const float* __restrict__ Wq, const float* __restrict__ bq,
                                               const float* __restrict__ Wk, const float* __restrict__ bk,
                                               const float* __restrict__ Wv, const float* __restrict__ bv,
                                               u16* __restrict__ Wcat, float* __restrict__ bcat) {
    const int idx = blockIdx.x * 256 + threadIdx.x;
    if (idx < NO_ * C_) {
        const int o = idx >> 9, c = idx & 511;
        float v;
        if (o < 64)       v = Wq[o * C_ + c];
        else if (o < 128) v = Wk[(o - 64) * C_ + c];
        else              v = Wv[(o - 128) * C_ + c];
        Wcat[idx] = f2bf(v);
    }
    if (idx < NO_) {
        float v = (idx < 64) ? bq[idx] : ((idx < 128) ? bk[idx - 64] : bv[idx - 128]);
        bcat[idx] = v;
    }
}

// ------------------------------------------------- K1: x[B,C,H,W] -> xT[b][w][h][c] bf16
__global__ __launch_bounds__(256) void k_transpose_x(const float* __restrict__ x, u16* __restrict__ xT) {
    __shared__ float tile[64][65];
    const int b  = blockIdx.x >> 7;
    const int h  = blockIdx.x & 127;
    const int c0 = (blockIdx.y >> 1) * 64;
    const int w0 = (blockIdx.y & 1) * 64;
    const int t = threadIdx.x, r = t >> 4, seg = t & 15;
    const float* xp = x + (size_t)b * C_ * H_ * W_ + (size_t)h * W_;
#pragma unroll
    for (int rr = 0; rr < 4; ++rr) {
        const int c = rr * 16 + r;
        float4 v = *(const float4*)(xp + (size_t)(c0 + c) * (H_ * W_) + w0 + seg * 4);
        tile[c][seg * 4 + 0] = v.x; tile[c][seg * 4 + 1] = v.y;
        tile[c][seg * 4 + 2] = v.z; tile[c][seg * 4 + 3] = v.w;
    }
    __syncthreads();
#pragma unroll
    for (int rr = 0; rr < 4; ++rr) {
        const int w = rr * 16 + r;
        ushort4 u;
        u.x = f2bf(tile[seg * 4 + 0][w]); u.y = f2bf(tile[seg * 4 + 1][w]);
        u.z = f2bf(tile[seg * 4 + 2][w]); u.w = f2bf(tile[seg * 4 + 3][w]);
        *(ushort4*)(xT + ((size_t)((b * W_ + w0 + w) * H_ + h)) * C_ + c0 + seg * 4) = u;
    }
}

// ------------------------------------------------- K2: GEMM, m201 4-phase/K-tile schedule
// BM=256, BN=256, BK=64, 8 waves (2M x 4N), wave tile 128x64, 32x32x16 MFMA.
// dbuf-2 LDS (2 x 64KB). Per K-tile: 4 phases {ds_read ∥ stage-unit, BAR, MFMA, BAR};
// staging ring: A(T+1)@T.p0, B0(T+2)@T.p1, B1(T+2)@T.p2; vmcnt(4) once per tile @p3.
// T2 seg-XOR swizzle (seg_phys = seg_log ^ (row&7)); gld16 dest linear,
// global source pre-swizzled. N=640 -> 3 n-tiles (256,256,128+pad).
__global__ __launch_bounds__(512, 2) void k_gemm(const u16* __restrict__ A, const u16* __restrict__ Wc,
                                                 const float* __restrict__ bias, u16* __restrict__ Call,
                                                 u16* __restrict__ vt) {
    __shared__ __align__(16) u16 smem[65536];   // 128 KB: 2 bufs of (A 16384 + B 16384) u16
    const int t = threadIdx.x;
    const int lane = t & 63;
    const int wave = t >> 6;
    const int wr = wave >> 2;          // M half (128 rows)
    const int wc = wave & 3;           // N quarter (64 cols)
    const int l31 = lane & 31;
    const int kh = lane >> 5;          // k-half within fragment

    // bijective XCD-chunk swizzle: 768 = 8 XCDs x 96; n fastest within a panel
    const int bid = blockIdx.x;
    const int wg = (bid & 7) * 96 + (bid >> 3);
    const int panel = wg / 3;
    const int n = wg - panel * 3;
    const int r0 = panel * 256;
    const int n0 = n * 256;

    // staging: thread t covers (row = t>>3 within each 64-row round, seg_phys = t&7)
    const int srow = t >> 3;
    const int slog = (t & 7) ^ (srow & 7);         // inverse-swizzled source segment
    const u16* gA = A + (size_t)(r0 + srow) * C_ + slog * 8;
    const u16* gBr[4];
#pragma unroll
    for (int i = 0; i < 4; ++i) {
        int row = n0 + i * 64 + srow;
        if (row > NO_ - 1) row = NO_ - 1;          // tail clamp (valid-but-unused)
        gBr[i] = Wc + (size_t)row * C_ + slog * 8;
    }

#define STG_A(T) do { u16* S_ = smem + (((T) & 1) * 32768); const int k0_ = (T) * 64;  \
        gld16(gA + k0_,             S_ + t * 8);                                       \
        gld16(gA + k0_ +  64 * C_,  S_ + 4096  + t * 8);                               \
        gld16(gA + k0_ + 128 * C_,  S_ + 8192  + t * 8);                               \
        gld16(gA + k0_ + 192 * C_,  S_ + 12288 + t * 8); } while (0)
#define STG_B0(T) do { u16* S_ = smem + (((T) & 1) * 32768) + 16384; const int k0_ = (T) * 64; \
        gld16(gBr[0] + k0_, S_ + t * 8);                                               \
        gld16(gBr[1] + k0_, S_ + 4096 + t * 8); } while (0)
#define STG_B1(T) do { u16* S_ = smem + (((T) & 1) * 32768) + 16384; const int k0_ = (T) * 64; \
        gld16(gBr[2] + k0_, S_ + 8192 + t * 8);                                        \
        gld16(gBr[3] + k0_, S_ + 12288 + t * 8); } while (0)

    f32x16 acc[4][2] = {};
    s16x8 fa[4], fb[2][4];

#define LDA(Ab, P) do { _Pragma("unroll") for (int kl = 0; kl < 4; ++kl) {             \
        const int rr = wr * 128 + (P) * 32 + l31;                                      \
        const int sb = kl * 2 + kh;                                                    \
        fa[kl] = *(const s16x8*)&(Ab)[rr * 64 + ((sb ^ (rr & 7)) * 8)]; } } while (0)
#define LDB(Bb) do { _Pragma("unroll") for (int ni = 0; ni < 2; ++ni)                  \
        _Pragma("unroll") for (int kl = 0; kl < 4; ++kl) {                             \
        const int rr = wc * 64 + ni * 32 + l31;                                        \
        const int sb = kl * 2 + kh;                                                    \
        fb[ni][kl] = *(const s16x8*)&(Bb)[rr * 64 + ((sb ^ (rr & 7)) * 8)]; } } while (0)
#define MM(P) do { __builtin_amdgcn_s_setprio(1);                                      \
        _Pragma("unroll") for (int kl = 0; kl < 4; ++kl)                               \
        _Pragma("unroll") for (int ni = 0; ni < 2; ++ni)                               \
            acc[(P)][ni] = __builtin_amdgcn_mfma_f32_32x32x16_bf16(                    \
                fa[kl], fb[ni][kl], acc[(P)][ni], 0, 0, 0);                            \
        __builtin_amdgcn_s_setprio(0); } while (0)
#define BAR() __builtin_amdgcn_s_barrier()

#define KTILE(T, VMST) do {                                                            \
        const u16* Ab_ = smem + (((T) & 1) * 32768);                                   \
        const u16* Bb_ = Ab_ + 16384;                                                  \
        /* p0 */ LDB(Bb_); LDA(Ab_, 0); if ((T) + 1 < 8) STG_A((T) + 1);               \
        BAR(); MM(0); BAR();                                                           \
        /* p1 */ LDA(Ab_, 1); if ((T) + 2 < 8) STG_B0((T) + 2);                        \
        BAR(); MM(1); BAR();                                                           \
        /* p2 */ LDA(Ab_, 2); if ((T) + 2 < 8) STG_B1((T) + 2);                        \
        BAR(); MM(2); BAR();                                                           \
        /* p3 */ LDA(Ab_, 3); VMST;                                                    \
        BAR(); MM(3); BAR();                                                           \
    } while (0)

    // prologue: tile0 fully + B of tile1 (A of tile1 staged at T0.p0)
    STG_A(0); STG_B0(0); STG_B1(0); STG_B0(1); STG_B1(1);
    asm volatile("s_waitcnt vmcnt(4)" ::: "memory");   // tile0 landed; B(1) in flight
    BAR();

    KTILE(0, asm volatile("s_waitcnt vmcnt(4)" ::: "memory"));
    KTILE(1, asm volatile("s_waitcnt vmcnt(4)" ::: "memory"));
    KTILE(2, asm volatile("s_waitcnt vmcnt(4)" ::: "memory"));
    KTILE(3, asm volatile("s_waitcnt vmcnt(4)" ::: "memory"));
    KTILE(4, asm volatile("s_waitcnt vmcnt(4)" ::: "memory"));
    KTILE(5, asm volatile("s_waitcnt vmcnt(4)" ::: "memory"));
    KTILE(6, asm volatile("s_waitcnt vmcnt(0)" ::: "memory"));
    KTILE(7, (void)0);

#undef KTILE
#undef BAR
#undef MM
#undef LDB
#undef LDA
#undef STG_B1
#undef STG_B0
#undef STG_A

    // C/D mapping (m74/m101): col = lane&31, row = (reg&3) + 8*(reg>>2) + 4*(lane>>5)
    const int bw0 = panel * 2;
    if (n == 0 && wc < 2) {
        // Q/K: cols o = wc*64 + ni*32 + l31 (0..127) -> Call[row][o]
#pragma unroll
        for (int ni = 0; ni < 2; ++ni) {
            const int o = wc * 64 + ni * 32 + l31;
            const float bz = bias[o];
#pragma unroll
            for (int mi = 0; mi < 4; ++mi)
#pragma unroll
                for (int rg = 0; rg < 16; ++rg) {
                    const int row = r0 + wr * 128 + mi * 32 + (rg & 3) + 8 * (rg >> 2) + 4 * kh;
                    Call[(size_t)row * 128 + o] = f2bf(acc[mi][ni][rg] + bz);
                }
        }
    }
    // V: transpose passes of 128 channels through T[128][264]
    u16* Tt = smem;
#pragma unroll
    for (int pass = 0; pass < 2; ++pass) {
        const int base = n0 + pass * 128;          // global col of pass start
        if (base < 128 || base >= NO_) continue;   // n=0 pass0 = Q/K; n=2 pass1 = OOB pad
        if ((wc >> 1) == pass) {
#pragma unroll
            for (int ni = 0; ni < 2; ++ni) {
                const int c_loc = (wc & 1) * 64 + ni * 32 + l31;    // 0..127
                const float bz = bias[base + c_loc];
#pragma unroll
                for (int mi = 0; mi < 4; ++mi)
#pragma unroll
                    for (int q = 0; q < 4; ++q) {
                        const int hb = wr * 128 + mi * 32 + q * 8 + 4 * kh;  // 4 consecutive rows
                        ushort4 u4;
                        u4.x = f2bf(acc[mi][ni][q * 4 + 0] + bz);
                        u4.y = f2bf(acc[mi][ni][q * 4 + 1] + bz);
                        u4.z = f2bf(acc[mi][ni][q * 4 + 2] + bz);
                        u4.w = f2bf(acc[mi][ni][q * 4 + 3] + bz);
                        *(ushort4*)&Tt[c_loc * 264 + hb] = u4;
                    }
            }
        }
        __syncthreads();
        {
            const int c_loc = t >> 2, h0 = (t & 3) * 64;
            const int cg = base - 128 + c_loc;                      // V channel 0..511
#pragma unroll
            for (int k = 0; k < 8; ++k) {
                const int h = h0 + k * 8;                           // 0..255
                const int bw = bw0 + (h >> 7);
                s16x8 v = *(const s16x8*)&Tt[c_loc * 264 + h];
                *(s16x8*)&vt[((size_t)bw * 512 + cg) * 128 + (h & 127)] = v;
            }
        }
        __syncthreads();
    }
}

// ------------------------------------------------- K4: per-(b,w) axial attention
__global__ __launch_bounds__(256) void k_attn(const u16* __restrict__ Call, const u16* __restrict__ vt,
                                              u16* __restrict__ outws) {
    __shared__ __align__(16) float E[128][132];
    __shared__ float Rinv[128];
    const int bw = blockIdx.x;
    const int t = threadIdx.x;
    const int lane = t & 63;
    const int wr = t >> 7;
    const int wc = (t >> 6) & 1;
    const int lr = lane & 15, lk = (lane >> 4) * 8;
    const size_t rowbase = (size_t)bw * 128;

    // ---- energy = Q K^T  (K-dim = 64 channels); Call stride 128
    f32x4 e[4][4] = {};
#pragma unroll
    for (int kk = 0; kk < 2; ++kk) {
        s16x8 fq[4], fk[4];
#pragma unroll
        for (int mi = 0; mi < 4; ++mi)
            fq[mi] = *(const s16x8*)&Call[(rowbase + wr * 64 + mi * 16 + lr) * 128 + kk * 32 + lk];
#pragma unroll
        for (int ni = 0; ni < 4; ++ni)
            fk[ni] = *(const s16x8*)&Call[(rowbase + wc * 64 + ni * 16 + lr) * 128 + 64 + kk * 32 + lk];
#pragma unroll
        for (int mi = 0; mi < 4; ++mi)
#pragma unroll
            for (int ni = 0; ni < 4; ++ni)
                e[mi][ni] = __builtin_amdgcn_mfma_f32_16x16x32_bf16(fq[mi], fk[ni], e[mi][ni], 0, 0, 0);
    }
#pragma unroll
    for (int mi = 0; mi < 4; ++mi)
#pragma unroll
        for (int ni = 0; ni < 4; ++ni)
#pragma unroll
            for (int j = 0; j < 4; ++j)
                E[wr * 64 + mi * 16 + (lane >> 4) * 4 + j][wc * 64 + ni * 16 + lr] = e[mi][ni][j];
    __syncthreads();

    // ---- softmax over g (rows h), exp in place, 2 threads per row
    {
        const int h = t >> 1, hf = (t & 1) * 64;
        float m = -1e30f;
        for (int i = 0; i < 64; ++i) m = fmaxf(m, E[h][hf + i]);
        m = fmaxf(m, __shfl_xor(m, 1));
        float s = 0.f;
        for (int i = 0; i < 64; ++i) {
            float p = __expf(E[h][hf + i] - m);
            E[h][hf + i] = p;
            s += p;
        }
        s += __shfl_xor(s, 1);
        if ((t & 1) == 0) Rinv[h] = 1.0f / s;
    }
    __syncthreads();

    float rv[4][4];
#pragma unroll
    for (int mi = 0; mi < 4; ++mi)
#pragma unroll
        for (int j = 0; j < 4; ++j)
            rv[mi][j] = Rinv[wr * 64 + mi * 16 + (lane >> 4) * 4 + j];

    // ---- P rows -> bf16 fragments ONCE
    s16x8 pa[4][4];
#pragma unroll
    for (int kk = 0; kk < 4; ++kk)
#pragma unroll
        for (int mi = 0; mi < 4; ++mi) {
            const float* ep = &E[wr * 64 + mi * 16 + lr][kk * 32 + lk];
            float4 v0 = *(const float4*)ep;
            float4 v1 = *(const float4*)(ep + 4);
            s16x8 a;
            a[0] = (short)f2bf(v0.x); a[1] = (short)f2bf(v0.y);
            a[2] = (short)f2bf(v0.z); a[3] = (short)f2bf(v0.w);
            a[4] = (short)f2bf(v1.x); a[5] = (short)f2bf(v1.y);
            a[6] = (short)f2bf(v1.z); a[7] = (short)f2bf(v1.w);
            pa[kk][mi] = a;
        }

    // ---- out = P V
    for (int cc = 0; cc < 4; ++cc) {
        f32x4 acc[4][4] = {};
#pragma unroll
        for (int kk = 0; kk < 4; ++kk) {
            s16x8 fb[4];
#pragma unroll
            for (int ni = 0; ni < 4; ++ni)
                fb[ni] = *(const s16x8*)&vt[((size_t)bw * 512 + cc * 128 + wc * 64 + ni * 16 + lr) * 128 + kk * 32 + lk];
#pragma unroll
            for (int mi = 0; mi < 4; ++mi)
#pragma unroll
                for (int ni = 0; ni < 4; ++ni)
                    acc[mi][ni] = __builtin_amdgcn_mfma_f32_16x16x32_bf16(pa[kk][mi], fb[ni], acc[mi][ni], 0, 0, 0);
        }
#pragma unroll
        for (int ni = 0; ni < 4; ++ni) {
            const int c = cc * 128 + wc * 64 + ni * 16 + lr;
#pragma unroll
            for (int mi = 0; mi < 4; ++mi)
#pragma unroll
                for (int j = 0; j < 4; ++j) {
                    const int hh = wr * 64 + mi * 16 + (lane >> 4) * 4 + j;
                    outws[(rowbase + hh) * 512 + c] = f2bf(acc[mi][ni][j] * rv[mi][j]);
                }
        }
    }
}

// ------------------------------------------------- K5: out = gamma*out_ws^T + x
__global__ __launch_bounds__(256) void k_merge(const u16* __restrict__ outws, const float* __restrict__ x,
                                               const float* __restrict__ gamma, float* __restrict__ out) {
    __shared__ float tile[64][65];
    const int b  = blockIdx.x >> 7;
    const int h  = blockIdx.x & 127;
    const int c0 = (blockIdx.y >> 1) * 64;
    const int w0 = (blockIdx.y & 1) * 64;
    const float g = gamma[0];
    const int t = threadIdx.x, r = t >> 4, seg = t & 15;
#pragma unroll
    for (int rr = 0; rr < 4; ++rr) {
        const int w = rr * 16 + r;
        ushort4 v = *(const ushort4*)(outws + ((size_t)((b * W_ + w0 + w) * H_) + h) * C_ + c0 + seg * 4);
        tile[w][seg * 4 + 0] = bf2f(v.x); tile[w][seg * 4 + 1] = bf2f(v.y);
        tile[w][seg * 4 + 2] = bf2f(v.z); tile[w][seg * 4 + 3] = bf2f(v.w);
    }
    __syncthreads();
#pragma unroll
    for (int rr = 0; rr < 4; ++rr) {
        const int c = rr * 16 + r;
        const size_t base = ((size_t)(b * C_ + c0 + c) * H_ + h) * W_ + w0 + seg * 4;
        float4 xv = *(const float4*)(x + base);
        float4 o;
        o.x = g * tile[seg * 4 + 0][c] + xv.x;
        o.y = g * tile[seg * 4 + 1][c] + xv.y;
        o.z = g * tile[seg * 4 + 2][c] + xv.z;
        o.w = g * tile[seg * 4 + 3][c] + xv.w;
        *(float4*)(out + base) = o;
    }
}

extern "C" void kernel_launch(void* const* d_in, const int* in_sizes, int n_in,
                              void* d_out, int out_size, void* d_ws, size_t ws_size,
                              hipStream_t stream) {
    const float* x     = (const float*)d_in[0];
    const float* Wq    = (const float*)d_in[1];
    const float* bq    = (const float*)d_in[2];
    const float* Wk    = (const float*)d_in[3];
    const float* bk    = (const float*)d_in[4];
    const float* Wv    = (const float*)d_in[5];
    const float* bv    = (const float*)d_in[6];
    const float* gamma = (const float*)d_in[7];

    char* ws = (char*)d_ws;
    u16*   Wcat  = (u16*)ws;                                   //   0.66 MB
    float* bcat  = (float*)(ws + 655360);                      //   2.5 KB
    u16*   xT    = (u16*)(ws + (1u << 20));                    //  67.1 MB  (reused as out_ws)
    u16*   Call  = (u16*)(ws + (1u << 20) + 67108864);         //  16.8 MB  (Q/K only, stride 128)
    u16*   outws = xT;                                         //  xT dead after k_gemm
    u16*   vt    = (u16*)d_out;                                //  first 67 MB of d_out; dead before k_merge writes

    k_convw<<<dim3((NO_ * C_ + 255) / 256), 256, 0, stream>>>(Wq, bq, Wk, bk, Wv, bv, Wcat, bcat);
    k_transpose_x<<<dim3(B_ * H_, 16), 256, 0, stream>>>(x, xT);
    k_gemm<<<dim3(768), 512, 0, stream>>>(xT, Wcat, bcat, Call, vt);
    k_attn<<<dim3(B_ * W_), 256, 0, stream>>>(Call, vt, outws);
    k_merge<<<dim3(B_ * H_, 16), 256, 0, stream>>>(outws, x, gamma, (float*)d_out);
}

// Round 9
// 195.324 us; speedup vs baseline: 1.0476x; 1.0452x over previous
//
#include <hip/hip_runtime.h>
#include <hip/hip_bf16.h>

typedef float f32x4  __attribute__((ext_vector_type(4)));
typedef float f32x16 __attribute__((ext_vector_type(16)));
typedef short s16x8  __attribute__((ext_vector_type(8)));
typedef unsigned short u16;

#define B_ 4
#define C_ 512
#define H_ 128
#define W_ 128
#define NO_ 640   // 64 q + 64 k + 512 v output channels

__device__ __forceinline__ u16 f2bf(float f) {
    __hip_bfloat16 h = __float2bfloat16(f);
    union { __hip_bfloat16 h; u16 u; } cv; cv.h = h; return cv.u;
}
__device__ __forceinline__ float bf2f(u16 u) {
    union { unsigned u; float f; } cv; cv.u = ((unsigned)u) << 16; return cv.f;
}

// async global->LDS, 16B per lane; LDS dest must be wave_base + lane*16
__device__ __forceinline__ void gld16(const u16* g, u16* l) {
    __builtin_amdgcn_global_load_lds(
        (const __attribute__((address_space(1))) void*)g,
        (__attribute__((address_space(3))) void*)l, 16, 0, 0);
}

// ---------------------------------------------------------------- K0: weights
__global__ __launch_bounds__(256) void k_convw(const float* __restrict__ Wq, const float* __restrict__ bq,
                                               const float* __restrict__ Wk, const float* __restrict__ bk,
                                               const float* __restrict__ Wv, const float* __restrict__ bv,
                                               u16* __restrict__ Wcat, float* __restrict__ bcat) {
    const int idx = blockIdx.x * 256 + threadIdx.x;
    if (idx < NO_ * C_) {
        const int o = idx >> 9, c = idx & 511;
        float v;
        if (o < 64)       v = Wq[o * C_ + c];
        else if (o < 128) v = Wk[(o - 64) * C_ + c];
        else              v = Wv[(o - 128) * C_ + c];
        Wcat[idx] = f2bf(v);
    }
    if (idx < NO_) {
        float v = (idx < 64) ? bq[idx] : ((idx < 128) ? bk[idx - 64] : bv[idx - 128]);
        bcat[idx] = v;
    }
}

// ------------------------------------------------- K1: x[B,C,H,W] -> xT[b][w][h][c] bf16
__global__ __launch_bounds__(256) void k_transpose_x(const float* __restrict__ x, u16* __restrict__ xT) {
    __shared__ float tile[64][65];
    const int b  = blockIdx.x >> 7;
    const int h  = blockIdx.x & 127;
    const int c0 = (blockIdx.y >> 1) * 64;
    const int w0 = (blockIdx.y & 1) * 64;
    const int t = threadIdx.x, r = t >> 4, seg = t & 15;
    const float* xp = x + (size_t)b * C_ * H_ * W_ + (size_t)h * W_;
#pragma unroll
    for (int rr = 0; rr < 4; ++rr) {
        const int c = rr * 16 + r;
        float4 v = *(const float4*)(xp + (size_t)(c0 + c) * (H_ * W_) + w0 + seg * 4);
        tile[c][seg * 4 + 0] = v.x; tile[c][seg * 4 + 1] = v.y;
        tile[c][seg * 4 + 2] = v.z; tile[c][seg * 4 + 3] = v.w;
    }
    __syncthreads();
#pragma unroll
    for (int rr = 0; rr < 4; ++rr) {
        const int w = rr * 16 + r;
        ushort4 u;
        u.x = f2bf(tile[seg * 4 + 0][w]); u.y = f2bf(tile[seg * 4 + 1][w]);
        u.z = f2bf(tile[seg * 4 + 2][w]); u.w = f2bf(tile[seg * 4 + 3][w]);
        *(ushort4*)(xT + ((size_t)((b * W_ + w0 + w) * H_ + h)) * C_ + c0 + seg * 4) = u;
    }
}

// ------------------------------------------------- K2: GEMM, 2-blocks/CU overlap structure
// BM=256, BN=128, BK=32, 4 waves (2M x 2N), wave tile 128x64, 32x32x16 MFMA.
// dbuf-2 LDS 48 KB (A 16K + B 8K per buf); epilogue T 66 KB -> LDS 66 KB -> 2 blocks/CU.
// Per K-step: STAGE(T+1) -> vmcnt(6) -> BAR -> 12 ds_read -> 16 MFMA -> BAR.
// Seg swizzle: seg_phys = seg_log ^ ((row>>1)&3); gld16 dest linear, source pre-swizzled.
__global__ __launch_bounds__(256, 2) void k_gemm(const u16* __restrict__ A, const u16* __restrict__ Wc,
                                                 const float* __restrict__ bias, u16* __restrict__ Call,
                                                 u16* __restrict__ vt) {
    __shared__ __align__(16) u16 smem[33792];   // 66 KB (dbuf uses first 24576)
    const int t = threadIdx.x;
    const int lane = t & 63;
    const int wave = t >> 6;
    const int wr = wave >> 1;          // M half (128 rows)
    const int wc = wave & 1;           // N half (64 cols)
    const int l31 = lane & 31;
    const int kh = lane >> 5;

    // bijective XCD-chunk swizzle: 1280 = 8 XCDs x 160; n fastest within a panel
    const int bid = blockIdx.x;
    const int wg = (bid & 7) * 160 + (bid >> 3);
    const int panel = wg / 5;
    const int n = wg - panel * 5;
    const int r0 = panel * 256;
    const int n0 = n * 128;

    // staging: round r covers rows r*64 + (t>>2), phys seg t&3; source seg pre-swizzled
    const int srow4 = t >> 2;
    const int sseg  = t & 3;
    const u16* gAr[4];
    const u16* gBr[2];
#pragma unroll
    for (int r = 0; r < 4; ++r) {
        const int rl = r * 64 + srow4;
        gAr[r] = A + (size_t)(r0 + rl) * C_ + (sseg ^ ((rl >> 1) & 3)) * 8;
    }
#pragma unroll
    for (int r = 0; r < 2; ++r) {
        const int rl = r * 64 + srow4;
        gBr[r] = Wc + (size_t)(n0 + rl) * C_ + (sseg ^ ((rl >> 1) & 3)) * 8;
    }

#define STAGE(KT) do {                                               \
        u16* S_ = smem + ((KT) & 1) * 12288;                         \
        const int k0_ = (KT) * 32;                                   \
        gld16(gAr[0] + k0_, S_ + t * 8);                             \
        gld16(gAr[1] + k0_, S_ + 2048 + t * 8);                      \
        gld16(gAr[2] + k0_, S_ + 4096 + t * 8);                      \
        gld16(gAr[3] + k0_, S_ + 6144 + t * 8);                      \
        gld16(gBr[0] + k0_, S_ + 8192 + t * 8);                      \
        gld16(gBr[1] + k0_, S_ + 10240 + t * 8);                     \
    } while (0)

    f32x16 acc[4][2] = {};
    STAGE(0);

#pragma unroll
    for (int T = 0; T < 16; ++T) {
        if (T < 15) {
            STAGE(T + 1);
            asm volatile("s_waitcnt vmcnt(6)" ::: "memory");
        } else {
            asm volatile("s_waitcnt vmcnt(0)" ::: "memory");
        }
        __builtin_amdgcn_s_barrier();
        const u16* Ab = smem + (T & 1) * 12288;
        const u16* Bb = Ab + 8192;
        s16x8 fa[2][4], fb[2][2];
#pragma unroll
        for (int kl = 0; kl < 2; ++kl) {
            const int sb = kl * 2 + kh;
#pragma unroll
            for (int mi = 0; mi < 4; ++mi) {
                const int rr = wr * 128 + mi * 32 + l31;
                fa[kl][mi] = *(const s16x8*)&Ab[rr * 32 + ((sb ^ ((rr >> 1) & 3)) * 8)];
            }
#pragma unroll
            for (int ni = 0; ni < 2; ++ni) {
                const int rr = wc * 64 + ni * 32 + l31;
                fb[kl][ni] = *(const s16x8*)&Bb[rr * 32 + ((sb ^ ((rr >> 1) & 3)) * 8)];
            }
        }
        __builtin_amdgcn_s_setprio(1);
#pragma unroll
        for (int kl = 0; kl < 2; ++kl)
#pragma unroll
            for (int mi = 0; mi < 4; ++mi)
#pragma unroll
                for (int ni = 0; ni < 2; ++ni)
                    acc[mi][ni] = __builtin_amdgcn_mfma_f32_32x32x16_bf16(
                        fa[kl][mi], fb[kl][ni], acc[mi][ni], 0, 0, 0);
        __builtin_amdgcn_s_setprio(0);
        __builtin_amdgcn_s_barrier();
    }
#undef STAGE

    // C/D mapping (m74/m101): col = lane&31, row = (reg&3) + 8*(reg>>2) + 4*(lane>>5)
    const int bw0 = panel * 2;
    if (n == 0) {
        // Q/K: cols o = wc*64 + ni*32 + l31 (0..127) -> Call[row][o]
#pragma unroll
        for (int ni = 0; ni < 2; ++ni) {
            const int o = wc * 64 + ni * 32 + l31;
            const float bz = bias[o];
#pragma unroll
            for (int mi = 0; mi < 4; ++mi)
#pragma unroll
                for (int rg = 0; rg < 16; ++rg) {
                    const int row = r0 + wr * 128 + mi * 32 + (rg & 3) + 8 * (rg >> 2) + 4 * kh;
                    Call[(size_t)row * 128 + o] = f2bf(acc[mi][ni][rg] + bz);
                }
        }
    } else {
        // V: single-pass transpose through T[128][264] -> vt[(bw*512 + cg)*128 + h]
        u16* Tt = smem;
#pragma unroll
        for (int ni = 0; ni < 2; ++ni) {
            const int c_loc = wc * 64 + ni * 32 + l31;              // 0..127
            const float bz = bias[n0 + c_loc];
#pragma unroll
            for (int mi = 0; mi < 4; ++mi)
#pragma unroll
                for (int q = 0; q < 4; ++q) {
                    const int hb = wr * 128 + mi * 32 + q * 8 + 4 * kh;  // 4 consecutive rows
                    ushort4 u4;
                    u4.x = f2bf(acc[mi][ni][q * 4 + 0] + bz);
                    u4.y = f2bf(acc[mi][ni][q * 4 + 1] + bz);
                    u4.z = f2bf(acc[mi][ni][q * 4 + 2] + bz);
                    u4.w = f2bf(acc[mi][ni][q * 4 + 3] + bz);
                    *(ushort4*)&Tt[c_loc * 264 + hb] = u4;
                }
        }
        __syncthreads();
        {
            const int c_loc = t >> 1;                               // 0..127
            const int hseg = t & 1;                                 // which bw of the pair
            const int cg = (n - 1) * 128 + c_loc;                   // V channel 0..511
            const int bw = bw0 + hseg;
            u16* dst = vt + ((size_t)bw * 512 + cg) * 128;
            const u16* src = &Tt[c_loc * 264 + hseg * 128];
#pragma unroll
            for (int k = 0; k < 16; ++k)
                *(s16x8*)&dst[k * 8] = *(const s16x8*)&src[k * 8];
        }
    }
}

// ------------------------------------------------- K4: per-(b,w) axial attention
__global__ __launch_bounds__(256) void k_attn(const u16* __restrict__ Call, const u16* __restrict__ vt,
                                              u16* __restrict__ outws) {
    __shared__ __align__(16) float E[128][132];
    __shared__ float Rinv[128];
    const int bw = blockIdx.x;
    const int t = threadIdx.x;
    const int lane = t & 63;
    const int wr = t >> 7;
    const int wc = (t >> 6) & 1;
    const int lr = lane & 15, lk = (lane >> 4) * 8;
    const size_t rowbase = (size_t)bw * 128;

    // ---- energy = Q K^T  (K-dim = 64 channels); Call stride 128
    f32x4 e[4][4] = {};
#pragma unroll
    for (int kk = 0; kk < 2; ++kk) {
        s16x8 fq[4], fk[4];
#pragma unroll
        for (int mi = 0; mi < 4; ++mi)
            fq[mi] = *(const s16x8*)&Call[(rowbase + wr * 64 + mi * 16 + lr) * 128 + kk * 32 + lk];
#pragma unroll
        for (int ni = 0; ni < 4; ++ni)
            fk[ni] = *(const s16x8*)&Call[(rowbase + wc * 64 + ni * 16 + lr) * 128 + 64 + kk * 32 + lk];
#pragma unroll
        for (int mi = 0; mi < 4; ++mi)
#pragma unroll
            for (int ni = 0; ni < 4; ++ni)
                e[mi][ni] = __builtin_amdgcn_mfma_f32_16x16x32_bf16(fq[mi], fk[ni], e[mi][ni], 0, 0, 0);
    }
#pragma unroll
    for (int mi = 0; mi < 4; ++mi)
#pragma unroll
        for (int ni = 0; ni < 4; ++ni)
#pragma unroll
            for (int j = 0; j < 4; ++j)
                E[wr * 64 + mi * 16 + (lane >> 4) * 4 + j][wc * 64 + ni * 16 + lr] = e[mi][ni][j];
    __syncthreads();

    // ---- softmax over g (rows h), exp in place, 2 threads per row
    {
        const int h = t >> 1, hf = (t & 1) * 64;
        float m = -1e30f;
        for (int i = 0; i < 64; ++i) m = fmaxf(m, E[h][hf + i]);
        m = fmaxf(m, __shfl_xor(m, 1));
        float s = 0.f;
        for (int i = 0; i < 64; ++i) {
            float p = __expf(E[h][hf + i] - m);
            E[h][hf + i] = p;
            s += p;
        }
        s += __shfl_xor(s, 1);
        if ((t & 1) == 0) Rinv[h] = 1.0f / s;
    }
    __syncthreads();

    float rv[4][4];
#pragma unroll
    for (int mi = 0; mi < 4; ++mi)
#pragma unroll
        for (int j = 0; j < 4; ++j)
            rv[mi][j] = Rinv[wr * 64 + mi * 16 + (lane >> 4) * 4 + j];

    // ---- P rows -> bf16 fragments ONCE
    s16x8 pa[4][4];
#pragma unroll
    for (int kk = 0; kk < 4; ++kk)
#pragma unroll
        for (int mi = 0; mi < 4; ++mi) {
            const float* ep = &E[wr * 64 + mi * 16 + lr][kk * 32 + lk];
            float4 v0 = *(const float4*)ep;
            float4 v1 = *(const float4*)(ep + 4);
            s16x8 a;
            a[0] = (short)f2bf(v0.x); a[1] = (short)f2bf(v0.y);
            a[2] = (short)f2bf(v0.z); a[3] = (short)f2bf(v0.w);
            a[4] = (short)f2bf(v1.x); a[5] = (short)f2bf(v1.y);
            a[6] = (short)f2bf(v1.z); a[7] = (short)f2bf(v1.w);
            pa[kk][mi] = a;
        }

    // ---- out = P V
    for (int cc = 0; cc < 4; ++cc) {
        f32x4 acc[4][4] = {};
#pragma unroll
        for (int kk = 0; kk < 4; ++kk) {
            s16x8 fb[4];
#pragma unroll
            for (int ni = 0; ni < 4; ++ni)
                fb[ni] = *(const s16x8*)&vt[((size_t)bw * 512 + cc * 128 + wc * 64 + ni * 16 + lr) * 128 + kk * 32 + lk];
#pragma unroll
            for (int mi = 0; mi < 4; ++mi)
#pragma unroll
                for (int ni = 0; ni < 4; ++ni)
                    acc[mi][ni] = __builtin_amdgcn_mfma_f32_16x16x32_bf16(pa[kk][mi], fb[ni], acc[mi][ni], 0, 0, 0);
        }
#pragma unroll
        for (int ni = 0; ni < 4; ++ni) {
            const int c = cc * 128 + wc * 64 + ni * 16 + lr;
#pragma unroll
            for (int mi = 0; mi < 4; ++mi)
#pragma unroll
                for (int j = 0; j < 4; ++j) {
                    const int hh = wr * 64 + mi * 16 + (lane >> 4) * 4 + j;
                    outws[(rowbase + hh) * 512 + c] = f2bf(acc[mi][ni][j] * rv[mi][j]);
                }
        }
    }
}

// ------------------------------------------------- K5: out = gamma*out_ws^T + x
__global__ __launch_bounds__(256) void k_merge(const u16* __restrict__ outws, const float* __restrict__ x,
                                               const float* __restrict__ gamma, float* __restrict__ out) {
    __shared__ float tile[64][65];
    const int b  = blockIdx.x >> 7;
    const int h  = blockIdx.x & 127;
    const int c0 = (blockIdx.y >> 1) * 64;
    const int w0 = (blockIdx.y & 1) * 64;
    const float g = gamma[0];
    const int t = threadIdx.x, r = t >> 4, seg = t & 15;
#pragma unroll
    for (int rr = 0; rr < 4; ++rr) {
        const int w = rr * 16 + r;
        ushort4 v = *(const ushort4*)(outws + ((size_t)((b * W_ + w0 + w) * H_) + h) * C_ + c0 + seg * 4);
        tile[w][seg * 4 + 0] = bf2f(v.x); tile[w][seg * 4 + 1] = bf2f(v.y);
        tile[w][seg * 4 + 2] = bf2f(v.z); tile[w][seg * 4 + 3] = bf2f(v.w);
    }
    __syncthreads();
#pragma unroll
    for (int rr = 0; rr < 4; ++rr) {
        const int c = rr * 16 + r;
        const size_t base = ((size_t)(b * C_ + c0 + c) * H_ + h) * W_ + w0 + seg * 4;
        float4 xv = *(const float4*)(x + base);
        float4 o;
        o.x = g * tile[seg * 4 + 0][c] + xv.x;
        o.y = g * tile[seg * 4 + 1][c] + xv.y;
        o.z = g * tile[seg * 4 + 2][c] + xv.z;
        o.w = g * tile[seg * 4 + 3][c] + xv.w;
        *(float4*)(out + base) = o;
    }
}

extern "C" void kernel_launch(void* const* d_in, const int* in_sizes, int n_in,
                              void* d_out, int out_size, void* d_ws, size_t ws_size,
                              hipStream_t stream) {
    const float* x     = (const float*)d_in[0];
    const float* Wq    = (const float*)d_in[1];
    const float* bq    = (const float*)d_in[2];
    const float* Wk    = (const float*)d_in[3];
    const float* bk    = (const float*)d_in[4];
    const float* Wv    = (const float*)d_in[5];
    const float* bv    = (const float*)d_in[6];
    const float* gamma = (const float*)d_in[7];

    char* ws = (char*)d_ws;
    u16*   Wcat  = (u16*)ws;                                   //   0.66 MB
    float* bcat  = (float*)(ws + 655360);                      //   2.5 KB
    u16*   xT    = (u16*)(ws + (1u << 20));                    //  67.1 MB  (reused as out_ws)
    u16*   Call  = (u16*)(ws + (1u << 20) + 67108864);         //  16.8 MB  (Q/K only, stride 128)
    u16*   outws = xT;                                         //  xT dead after k_gemm
    u16*   vt    = (u16*)d_out;                                //  first 67 MB of d_out; dead before k_merge writes

    k_convw<<<dim3((NO_ * C_ + 255) / 256), 256, 0, stream>>>(Wq, bq, Wk, bk, Wv, bv, Wcat, bcat);
    k_transpose_x<<<dim3(B_ * H_, 16), 256, 0, stream>>>(x, xT);
    k_gemm<<<dim3(1280), 256, 0, stream>>>(xT, Wcat, bcat, Call, vt);
    k_attn<<<dim3(B_ * W_), 256, 0, stream>>>(Call, vt, outws);
    k_merge<<<dim3(B_ * H_, 16), 256, 0, stream>>>(outws, x, gamma, (float*)d_out);
}

// Round 10
// 192.461 us; speedup vs baseline: 1.0632x; 1.0149x over previous
//
#include <hip/hip_runtime.h>
#include <hip/hip_bf16.h>

typedef float f32x4  __attribute__((ext_vector_type(4)));
typedef short s16x8  __attribute__((ext_vector_type(8)));
typedef unsigned short u16;

#define B_ 4
#define C_ 512
#define H_ 128
#define W_ 128
#define NO_ 640   // 64 q + 64 k + 512 v output channels

__device__ __forceinline__ u16 f2bf(float f) {
    __hip_bfloat16 h = __float2bfloat16(f);
    union { __hip_bfloat16 h; u16 u; } cv; cv.h = h; return cv.u;
}
__device__ __forceinline__ float bf2f(u16 u) {
    union { unsigned u; float f; } cv; cv.u = ((unsigned)u) << 16; return cv.f;
}

// async global->LDS, 16B per lane; LDS dest must be wave_base + lane*16
__device__ __forceinline__ void gld16(const u16* g, u16* l) {
    __builtin_amdgcn_global_load_lds(
        (const __attribute__((address_space(1))) void*)g,
        (__attribute__((address_space(3))) void*)l, 16, 0, 0);
}

// ---------------------------------------------------------------- K0: weights
__global__ __launch_bounds__(256) void k_convw(const float* __restrict__ Wq, const float* __restrict__ bq,
                                               const float* __restrict__ Wk, const float* __restrict__ bk,
                                               const float* __restrict__ Wv, const float* __restrict__ bv,
                                               u16* __restrict__ Wcat, float* __restrict__ bcat) {
    const int idx = blockIdx.x * 256 + threadIdx.x;
    if (idx < NO_ * C_) {
        const int o = idx >> 9, c = idx & 511;
        float v;
        if (o < 64)       v = Wq[o * C_ + c];
        else if (o < 128) v = Wk[(o - 64) * C_ + c];
        else              v = Wv[(o - 128) * C_ + c];
        Wcat[idx] = f2bf(v);
    }
    if (idx < NO_) {
        float v = (idx < 64) ? bq[idx] : ((idx < 128) ? bk[idx - 64] : bv[idx - 128]);
        bcat[idx] = v;
    }
}

// ------------------------------------------------- K1: x[B,C,H,W] -> xT[b][w][h][c] bf16
__global__ __launch_bounds__(256) void k_transpose_x(const float* __restrict__ x, u16* __restrict__ xT) {
    __shared__ float tile[64][65];
    const int b  = blockIdx.x >> 7;
    const int h  = blockIdx.x & 127;
    const int c0 = (blockIdx.y >> 1) * 64;
    const int w0 = (blockIdx.y & 1) * 64;
    const int t = threadIdx.x, r = t >> 4, seg = t & 15;
    const float* xp = x + (size_t)b * C_ * H_ * W_ + (size_t)h * W_;
#pragma unroll
    for (int rr = 0; rr < 4; ++rr) {
        const int c = rr * 16 + r;
        float4 v = *(const float4*)(xp + (size_t)(c0 + c) * (H_ * W_) + w0 + seg * 4);
        tile[c][seg * 4 + 0] = v.x; tile[c][seg * 4 + 1] = v.y;
        tile[c][seg * 4 + 2] = v.z; tile[c][seg * 4 + 3] = v.w;
    }
    __syncthreads();
#pragma unroll
    for (int rr = 0; rr < 4; ++rr) {
        const int w = rr * 16 + r;
        ushort4 u;
        u.x = f2bf(tile[seg * 4 + 0][w]); u.y = f2bf(tile[seg * 4 + 1][w]);
        u.z = f2bf(tile[seg * 4 + 2][w]); u.w = f2bf(tile[seg * 4 + 3][w]);
        *(ushort4*)(xT + ((size_t)((b * W_ + w0 + w) * H_ + h)) * C_ + c0 + seg * 4) = u;
    }
}

// ------------------------------------------------- K2: GEMM, concurrency-first structure
// BM=128, BN=128, BK=64, 4 waves (2M x 2N), 16x16x32 MFMA, single-buffered staging.
// LDS = max(32 KB staging, 34.8 KB epilogue T) = 34.8 KB -> 4 blocks/CU;
// __launch_bounds__(256,4) pins VGPR<=128 -> 16 waves/CU. Plain syncthreads pair
// per K-step (m97 structure); other resident blocks hide the drain (m114).
// Swizzle: seg_phys = seg_log ^ (row&7) (128B rows = 32 banks, row doesn't move bank);
// gld16 dest linear, global source pre-swizzled.
__global__ __launch_bounds__(256, 4) void k_gemm(const u16* __restrict__ A, const u16* __restrict__ Wc,
                                                 const float* __restrict__ bias, u16* __restrict__ Call,
                                                 u16* __restrict__ vt) {
    __shared__ __align__(16) u16 smem[17408];   // 34.8 KB
    const int t = threadIdx.x;
    const int lane = t & 63;
    const int wave = t >> 6;
    const int wr = wave >> 1;          // M half (64 rows)
    const int wc = wave & 1;           // N half (64 cols)
    const int lr = lane & 15;
    const int q4 = lane >> 4;          // 0..3

    // bijective XCD-chunk swizzle: 2560 = 8 XCDs x 320; n fastest within a panel
    const int bid = blockIdx.x;
    const int wg = (bid & 7) * 320 + (bid >> 3);
    const int panel = wg / 5;          // = bw (0..511)
    const int n = wg - panel * 5;
    const int r0 = panel * 128;
    const int n0 = n * 128;

    // staging: thread t covers row srow (32 rows/round), slot t&7; source pre-swizzled
    const int srow = t >> 3;           // 0..31
    const int slog = (t & 7) ^ (srow & 7);
    const u16* gA = A  + (size_t)(r0 + srow) * C_ + slog * 8;
    const u16* gB = Wc + (size_t)(n0 + srow) * C_ + slog * 8;

    f32x4 acc[4][4] = {};
#pragma unroll
    for (int T = 0; T < 8; ++T) {
        const int k0 = T * 64;
#pragma unroll
        for (int r = 0; r < 4; ++r) {
            gld16(gA + (size_t)r * 32 * C_ + k0, &smem[r * 2048 + t * 8]);
            gld16(gB + (size_t)r * 32 * C_ + k0, &smem[8192 + r * 2048 + t * 8]);
        }
        __syncthreads();               // drains vmcnt(0): tile visible
#pragma unroll
        for (int ksl = 0; ksl < 2; ++ksl) {
            const int sl = ksl * 4 + q4;       // logical 16B segment in 128B row
            s16x8 fa[4], fb[4];
#pragma unroll
            for (int mi = 0; mi < 4; ++mi) {
                const int rr = wr * 64 + mi * 16 + lr;
                fa[mi] = *(const s16x8*)&smem[rr * 64 + ((sl ^ (rr & 7)) * 8)];
            }
#pragma unroll
            for (int ni = 0; ni < 4; ++ni) {
                const int rr = wc * 64 + ni * 16 + lr;
                fb[ni] = *(const s16x8*)&smem[8192 + rr * 64 + ((sl ^ (rr & 7)) * 8)];
            }
            __builtin_amdgcn_s_setprio(1);
#pragma unroll
            for (int mi = 0; mi < 4; ++mi)
#pragma unroll
                for (int ni = 0; ni < 4; ++ni)
                    acc[mi][ni] = __builtin_amdgcn_mfma_f32_16x16x32_bf16(
                        fa[mi], fb[ni], acc[mi][ni], 0, 0, 0);
            __builtin_amdgcn_s_setprio(0);
        }
        __syncthreads();               // reads done before next stage overwrites
    }

    // C/D mapping (m89/m91): col = lane&15, row = (lane>>4)*4 + j
    if (n == 0) {
        // Q/K: Call[row][o], o = wc*64 + ni*16 + lr (0..127)
#pragma unroll
        for (int ni = 0; ni < 4; ++ni) {
            const int o = wc * 64 + ni * 16 + lr;
            const float bz = bias[o];
#pragma unroll
            for (int mi = 0; mi < 4; ++mi)
#pragma unroll
                for (int j = 0; j < 4; ++j) {
                    const int rg = r0 + wr * 64 + mi * 16 + q4 * 4 + j;
                    Call[(size_t)rg * 128 + o] = f2bf(acc[mi][ni][j] + bz);
                }
        }
    } else {
        // V: transpose through T[128][136] -> vt[(bw*512 + cg)*128 + h]
        u16* Tt = smem;
#pragma unroll
        for (int ni = 0; ni < 4; ++ni) {
            const int c_loc = wc * 64 + ni * 16 + lr;        // 0..127
            const float bz = bias[n0 + c_loc];
#pragma unroll
            for (int mi = 0; mi < 4; ++mi) {
                const int h = wr * 64 + mi * 16 + q4 * 4;    // 4 consecutive h (j=0..3)
                ushort4 u4;
                u4.x = f2bf(acc[mi][ni][0] + bz);
                u4.y = f2bf(acc[mi][ni][1] + bz);
                u4.z = f2bf(acc[mi][ni][2] + bz);
                u4.w = f2bf(acc[mi][ni][3] + bz);
                *(ushort4*)&Tt[c_loc * 136 + h] = u4;
            }
        }
        __syncthreads();
        {
            const int c_loc = t >> 1;                        // 0..127
            const int half  = t & 1;                         // h half (64)
            const int cg = (n - 1) * 128 + c_loc;            // V channel 0..511
            u16* dst = vt + ((size_t)panel * 512 + cg) * 128 + half * 64;
            const u16* src = &Tt[c_loc * 136 + half * 64];
#pragma unroll
            for (int k = 0; k < 8; ++k)
                *(s16x8*)&dst[k * 8] = *(const s16x8*)&src[k * 8];
        }
    }
}

// ------------------------------------------------- K4: per-(b,w) axial attention
__global__ __launch_bounds__(256) void k_attn(const u16* __restrict__ Call, const u16* __restrict__ vt,
                                              u16* __restrict__ outws) {
    __shared__ __align__(16) float E[128][132];
    __shared__ float Rinv[128];
    const int bw = blockIdx.x;
    const int t = threadIdx.x;
    const int lane = t & 63;
    const int wr = t >> 7;
    const int wc = (t >> 6) & 1;
    const int lr = lane & 15, lk = (lane >> 4) * 8;
    const size_t rowbase = (size_t)bw * 128;

    // ---- energy = Q K^T  (K-dim = 64 channels); Call stride 128
    f32x4 e[4][4] = {};
#pragma unroll
    for (int kk = 0; kk < 2; ++kk) {
        s16x8 fq[4], fk[4];
#pragma unroll
        for (int mi = 0; mi < 4; ++mi)
            fq[mi] = *(const s16x8*)&Call[(rowbase + wr * 64 + mi * 16 + lr) * 128 + kk * 32 + lk];
#pragma unroll
        for (int ni = 0; ni < 4; ++ni)
            fk[ni] = *(const s16x8*)&Call[(rowbase + wc * 64 + ni * 16 + lr) * 128 + 64 + kk * 32 + lk];
#pragma unroll
        for (int mi = 0; mi < 4; ++mi)
#pragma unroll
            for (int ni = 0; ni < 4; ++ni)
                e[mi][ni] = __builtin_amdgcn_mfma_f32_16x16x32_bf16(fq[mi], fk[ni], e[mi][ni], 0, 0, 0);
    }
#pragma unroll
    for (int mi = 0; mi < 4; ++mi)
#pragma unroll
        for (int ni = 0; ni < 4; ++ni)
#pragma unroll
            for (int j = 0; j < 4; ++j)
                E[wr * 64 + mi * 16 + (lane >> 4) * 4 + j][wc * 64 + ni * 16 + lr] = e[mi][ni][j];
    __syncthreads();

    // ---- softmax over g (rows h), exp in place, 2 threads per row
    {
        const int h = t >> 1, hf = (t & 1) * 64;
        float m = -1e30f;
        for (int i = 0; i < 64; ++i) m = fmaxf(m, E[h][hf + i]);
        m = fmaxf(m, __shfl_xor(m, 1));
        float s = 0.f;
        for (int i = 0; i < 64; ++i) {
            float p = __expf(E[h][hf + i] - m);
            E[h][hf + i] = p;
            s += p;
        }
        s += __shfl_xor(s, 1);
        if ((t & 1) == 0) Rinv[h] = 1.0f / s;
    }
    __syncthreads();

    float rv[4][4];
#pragma unroll
    for (int mi = 0; mi < 4; ++mi)
#pragma unroll
        for (int j = 0; j < 4; ++j)
            rv[mi][j] = Rinv[wr * 64 + mi * 16 + (lane >> 4) * 4 + j];

    // ---- P rows -> bf16 fragments ONCE
    s16x8 pa[4][4];
#pragma unroll
    for (int kk = 0; kk < 4; ++kk)
#pragma unroll
        for (int mi = 0; mi < 4; ++mi) {
            const float* ep = &E[wr * 64 + mi * 16 + lr][kk * 32 + lk];
            float4 v0 = *(const float4*)ep;
            float4 v1 = *(const float4*)(ep + 4);
            s16x8 a;
            a[0] = (short)f2bf(v0.x); a[1] = (short)f2bf(v0.y);
            a[2] = (short)f2bf(v0.z); a[3] = (short)f2bf(v0.w);
            a[4] = (short)f2bf(v1.x); a[5] = (short)f2bf(v1.y);
            a[6] = (short)f2bf(v1.z); a[7] = (short)f2bf(v1.w);
            pa[kk][mi] = a;
        }

    // ---- out = P V
    for (int cc = 0; cc < 4; ++cc) {
        f32x4 acc[4][4] = {};
#pragma unroll
        for (int kk = 0; kk < 4; ++kk) {
            s16x8 fb[4];
#pragma unroll
            for (int ni = 0; ni < 4; ++ni)
                fb[ni] = *(const s16x8*)&vt[((size_t)bw * 512 + cc * 128 + wc * 64 + ni * 16 + lr) * 128 + kk * 32 + lk];
#pragma unroll
            for (int mi = 0; mi < 4; ++mi)
#pragma unroll
                for (int ni = 0; ni < 4; ++ni)
                    acc[mi][ni] = __builtin_amdgcn_mfma_f32_16x16x32_bf16(pa[kk][mi], fb[ni], acc[mi][ni], 0, 0, 0);
        }
#pragma unroll
        for (int ni = 0; ni < 4; ++ni) {
            const int c = cc * 128 + wc * 64 + ni * 16 + lr;
#pragma unroll
            for (int mi = 0; mi < 4; ++mi)
#pragma unroll
                for (int j = 0; j < 4; ++j) {
                    const int hh = wr * 64 + mi * 16 + (lane >> 4) * 4 + j;
                    outws[(rowbase + hh) * 512 + c] = f2bf(acc[mi][ni][j] * rv[mi][j]);
                }
        }
    }
}

// ------------------------------------------------- K5: out = gamma*out_ws^T + x
__global__ __launch_bounds__(256) void k_merge(const u16* __restrict__ outws, const float* __restrict__ x,
                                               const float* __restrict__ gamma, float* __restrict__ out) {
    __shared__ float tile[64][65];
    const int b  = blockIdx.x >> 7;
    const int h  = blockIdx.x & 127;
    const int c0 = (blockIdx.y >> 1) * 64;
    const int w0 = (blockIdx.y & 1) * 64;
    const float g = gamma[0];
    const int t = threadIdx.x, r = t >> 4, seg = t & 15;
#pragma unroll
    for (int rr = 0; rr < 4; ++rr) {
        const int w = rr * 16 + r;
        ushort4 v = *(const ushort4*)(outws + ((size_t)((b * W_ + w0 + w) * H_) + h) * C_ + c0 + seg * 4);
        tile[w][seg * 4 + 0] = bf2f(v.x); tile[w][seg * 4 + 1] = bf2f(v.y);
        tile[w][seg * 4 + 2] = bf2f(v.z); tile[w][seg * 4 + 3] = bf2f(v.w);
    }
    __syncthreads();
#pragma unroll
    for (int rr = 0; rr < 4; ++rr) {
        const int c = rr * 16 + r;
        const size_t base = ((size_t)(b * C_ + c0 + c) * H_ + h) * W_ + w0 + seg * 4;
        float4 xv = *(const float4*)(x + base);
        float4 o;
        o.x = g * tile[seg * 4 + 0][c] + xv.x;
        o.y = g * tile[seg * 4 + 1][c] + xv.y;
        o.z = g * tile[seg * 4 + 2][c] + xv.z;
        o.w = g * tile[seg * 4 + 3][c] + xv.w;
        *(float4*)(out + base) = o;
    }
}

extern "C" void kernel_launch(void* const* d_in, const int* in_sizes, int n_in,
                              void* d_out, int out_size, void* d_ws, size_t ws_size,
                              hipStream_t stream) {
    const float* x     = (const float*)d_in[0];
    const float* Wq    = (const float*)d_in[1];
    const float* bq    = (const float*)d_in[2];
    const float* Wk    = (const float*)d_in[3];
    const float* bk    = (const float*)d_in[4];
    const float* Wv    = (const float*)d_in[5];
    const float* bv    = (const float*)d_in[6];
    const float* gamma = (const float*)d_in[7];

    char* ws = (char*)d_ws;
    u16*   Wcat  = (u16*)ws;                                   //   0.66 MB
    float* bcat  = (float*)(ws + 655360);                      //   2.5 KB
    u16*   xT    = (u16*)(ws + (1u << 20));                    //  67.1 MB  (reused as out_ws)
    u16*   Call  = (u16*)(ws + (1u << 20) + 67108864);         //  16.8 MB  (Q/K only, stride 128)
    u16*   outws = xT;                                         //  xT dead after k_gemm
    u16*   vt    = (u16*)d_out;                                //  first 67 MB of d_out; dead before k_merge writes

    k_convw<<<dim3((NO_ * C_ + 255) / 256), 256, 0, stream>>>(Wq, bq, Wk, bk, Wv, bv, Wcat, bcat);
    k_transpose_x<<<dim3(B_ * H_, 16), 256, 0, stream>>>(x, xT);
    k_gemm<<<dim3(2560), 256, 0, stream>>>(xT, Wcat, bcat, Call, vt);
    k_attn<<<dim3(B_ * W_), 256, 0, stream>>>(Call, vt, outws);
    k_merge<<<dim3(B_ * H_, 16), 256, 0, stream>>>(outws, x, gamma, (float*)d_out);
}